// Round 1
// baseline (354.926 us; speedup 1.0000x reference)
//
#include <hip/hip_runtime.h>
#include <hip/hip_bf16.h>

#define D_DIM 512
#define K_CL  2048
#define BM    32

typedef short s8v __attribute__((ext_vector_type(8)));
typedef float f4v __attribute__((ext_vector_type(4)));

// ---------------- prep: fp32 -> bf16 + row sum-of-squares (fp32) -------------
// one wave (64 lanes) per row of 512 floats; lane handles 8 consecutive elems
__global__ void prep_kernel(const float* __restrict__ src,
                            ushort* __restrict__ dst,
                            float* __restrict__ norms,
                            int nrows) {
    int gwave = (int)((blockIdx.x * blockDim.x + threadIdx.x) >> 6);
    int lane  = threadIdx.x & 63;
    if (gwave >= nrows) return;

    const float* row = src + (size_t)gwave * D_DIM + lane * 8;
    float4 v0 = *reinterpret_cast<const float4*>(row);
    float4 v1 = *reinterpret_cast<const float4*>(row + 4);

    float ss = v0.x * v0.x + v0.y * v0.y + v0.z * v0.z + v0.w * v0.w
             + v1.x * v1.x + v1.y * v1.y + v1.z * v1.z + v1.w * v1.w;

    alignas(16) __hip_bfloat16 h[8];
    h[0] = __float2bfloat16(v0.x); h[1] = __float2bfloat16(v0.y);
    h[2] = __float2bfloat16(v0.z); h[3] = __float2bfloat16(v0.w);
    h[4] = __float2bfloat16(v1.x); h[5] = __float2bfloat16(v1.y);
    h[6] = __float2bfloat16(v1.z); h[7] = __float2bfloat16(v1.w);
    *reinterpret_cast<uint4*>(dst + (size_t)gwave * D_DIM + lane * 8) =
        *reinterpret_cast<const uint4*>(h);

    #pragma unroll
    for (int off = 32; off > 0; off >>= 1) ss += __shfl_down(ss, off, 64);
    if (lane == 0) norms[gwave] = ss;
}

// ------------- fused bf16 GEMM (F . P^T) + distance/sim/softmax --------------
// block: 32 rows x 2048 cols (full softmax row in-block). 8 waves, each wave
// owns 32 rows x 256 cols = 2 row-tiles x 16 col-tiles of 16x16 MFMA output.
__global__ __launch_bounds__(512, 2)
void gemm_softmax_kernel(const ushort* __restrict__ Fb,
                         const ushort* __restrict__ Pb,
                         const float* __restrict__ f2,
                         const float* __restrict__ p2,
                         float* __restrict__ out) {
    const int wid  = threadIdx.x >> 6;     // 0..7
    const int lane = threadIdx.x & 63;
    const int lr   = lane & 15;            // A-row / B-col / C-col within tile
    const int lg   = lane >> 4;            // k-group (and C row group)
    const int row0 = blockIdx.x * BM;
    const int col0 = wid * 256;

    __shared__ float partial[8][BM];
    __shared__ float inv_total[BM];

    f4v acc[2][16];
    #pragma unroll
    for (int rt = 0; rt < 2; ++rt)
        #pragma unroll
        for (int ct = 0; ct < 16; ++ct)
            acc[rt][ct] = (f4v){0.f, 0.f, 0.f, 0.f};

    // A frag: lane holds F[row0 + rt*16 + lr][ds + 8*lg .. +7]   (16B load)
    // B frag: lane holds P[col0 + ct*16 + lr][ds + 8*lg .. +7]   (16B load)
    const ushort* Abase = Fb + (size_t)(row0 + lr) * D_DIM + lg * 8;
    const ushort* Bbase = Pb + (size_t)(col0 + lr) * D_DIM + lg * 8;

    for (int ds = 0; ds < D_DIM; ds += 32) {
        s8v a0 = *reinterpret_cast<const s8v*>(Abase + ds);
        s8v a1 = *reinterpret_cast<const s8v*>(Abase + (size_t)16 * D_DIM + ds);
        #pragma unroll
        for (int ct = 0; ct < 16; ++ct) {
            s8v b = *reinterpret_cast<const s8v*>(Bbase + (size_t)ct * 16 * D_DIM + ds);
            acc[0][ct] = __builtin_amdgcn_mfma_f32_16x16x32_bf16(a0, b, acc[0][ct], 0, 0, 0);
            acc[1][ct] = __builtin_amdgcn_mfma_f32_16x16x32_bf16(a1, b, acc[1][ct], 0, 0, 0);
        }
    }

    // ---- epilogue: sq = f2 + p2 - 2*fp ; sim = 1/(1+sqrt(sq)) ; e = exp(sim)
    float pf2[2][4];
    #pragma unroll
    for (int rt = 0; rt < 2; ++rt)
        #pragma unroll
        for (int r = 0; r < 4; ++r)
            pf2[rt][r] = f2[row0 + rt * 16 + 4 * lg + r];

    float pp2[16];
    #pragma unroll
    for (int ct = 0; ct < 16; ++ct)
        pp2[ct] = p2[col0 + ct * 16 + lr];

    float rsum[2][4] = {{0.f, 0.f, 0.f, 0.f}, {0.f, 0.f, 0.f, 0.f}};
    #pragma unroll
    for (int rt = 0; rt < 2; ++rt)
        #pragma unroll
        for (int ct = 0; ct < 16; ++ct)
            #pragma unroll
            for (int r = 0; r < 4; ++r) {
                float sq = pf2[rt][r] + pp2[ct] - 2.0f * acc[rt][ct][r];
                sq = fmaxf(sq, 0.0f);
                float dist = sqrtf(sq);
                float e = __expf(1.0f / (1.0f + dist));
                acc[rt][ct][r] = e;
                rsum[rt][r] += e;
            }

    // reduce across the 16 lanes that share the same rows (vary only in col)
    #pragma unroll
    for (int rt = 0; rt < 2; ++rt)
        #pragma unroll
        for (int r = 0; r < 4; ++r) {
            float v = rsum[rt][r];
            #pragma unroll
            for (int m = 1; m < 16; m <<= 1) v += __shfl_xor(v, m, 64);
            rsum[rt][r] = v;
        }

    if (lr == 0) {
        #pragma unroll
        for (int rt = 0; rt < 2; ++rt)
            #pragma unroll
            for (int r = 0; r < 4; ++r)
                partial[wid][rt * 16 + 4 * lg + r] = rsum[rt][r];
    }
    __syncthreads();

    if (threadIdx.x < BM) {
        float s = 0.f;
        #pragma unroll
        for (int w = 0; w < 8; ++w) s += partial[w][threadIdx.x];
        inv_total[threadIdx.x] = 1.0f / s;
    }
    __syncthreads();

    float pinv[2][4];
    #pragma unroll
    for (int rt = 0; rt < 2; ++rt)
        #pragma unroll
        for (int r = 0; r < 4; ++r)
            pinv[rt][r] = inv_total[rt * 16 + 4 * lg + r];

    #pragma unroll
    for (int rt = 0; rt < 2; ++rt)
        #pragma unroll
        for (int ct = 0; ct < 16; ++ct)
            #pragma unroll
            for (int r = 0; r < 4; ++r) {
                int row = row0 + rt * 16 + 4 * lg + r;
                int col = col0 + ct * 16 + lr;
                out[(size_t)row * K_CL + col] = acc[rt][ct][r] * pinv[rt][r];
            }
}

extern "C" void kernel_launch(void* const* d_in, const int* in_sizes, int n_in,
                              void* d_out, int out_size, void* d_ws, size_t ws_size,
                              hipStream_t stream) {
    const float* features   = (const float*)d_in[0];
    const float* prototypes = (const float*)d_in[1];
    float* out = (float*)d_out;

    const int n = in_sizes[0] / D_DIM;   // 32768
    const int k = in_sizes[1] / D_DIM;   // 2048

    char* ws = (char*)d_ws;
    ushort* Fb = (ushort*)ws;                                    // n*D*2 bytes
    ushort* Pb = (ushort*)(ws + (size_t)n * D_DIM * 2);          // k*D*2 bytes
    float*  f2 = (float*)(ws + (size_t)(n + k) * D_DIM * 2);     // n floats
    float*  p2 = f2 + n;                                         // k floats

    // one wave per row; 4 waves (256 threads) per block
    prep_kernel<<<dim3((n + 3) / 4), dim3(256), 0, stream>>>(features, Fb, f2, n);
    prep_kernel<<<dim3((k + 3) / 4), dim3(256), 0, stream>>>(prototypes, Pb, p2, k);

    gemm_softmax_kernel<<<dim3(n / BM), dim3(512), 0, stream>>>(Fb, Pb, f2, p2, out);
}

// Round 2
// 316.242 us; speedup vs baseline: 1.1223x; 1.1223x over previous
//
#include <hip/hip_runtime.h>
#include <hip/hip_bf16.h>

#define D_DIM 512
#define K_CL  2048
#define BM    32

#define AS1 __attribute__((address_space(1)))
#define AS3 __attribute__((address_space(3)))

typedef short s8v __attribute__((ext_vector_type(8)));
typedef float f4v __attribute__((ext_vector_type(4)));

__device__ __forceinline__ void gload16(const void* g, void* l) {
    // async global->LDS, 16B per lane; LDS dest = wave-uniform base + lane*16
    __builtin_amdgcn_global_load_lds((const AS1 void*)g, (AS3 void*)l, 16, 0, 0);
}

// ---------------- prep: fp32 -> bf16 + row sum-of-squares (fp32) -------------
__global__ void prep_kernel(const float* __restrict__ src,
                            ushort* __restrict__ dst,
                            float* __restrict__ norms,
                            int nrows) {
    int gwave = (int)((blockIdx.x * blockDim.x + threadIdx.x) >> 6);
    int lane  = threadIdx.x & 63;
    if (gwave >= nrows) return;

    const float* row = src + (size_t)gwave * D_DIM + lane * 8;
    float4 v0 = *reinterpret_cast<const float4*>(row);
    float4 v1 = *reinterpret_cast<const float4*>(row + 4);

    float ss = v0.x * v0.x + v0.y * v0.y + v0.z * v0.z + v0.w * v0.w
             + v1.x * v1.x + v1.y * v1.y + v1.z * v1.z + v1.w * v1.w;

    alignas(16) __hip_bfloat16 h[8];
    h[0] = __float2bfloat16(v0.x); h[1] = __float2bfloat16(v0.y);
    h[2] = __float2bfloat16(v0.z); h[3] = __float2bfloat16(v0.w);
    h[4] = __float2bfloat16(v1.x); h[5] = __float2bfloat16(v1.y);
    h[6] = __float2bfloat16(v1.z); h[7] = __float2bfloat16(v1.w);
    *reinterpret_cast<uint4*>(dst + (size_t)gwave * D_DIM + lane * 8) =
        *reinterpret_cast<const uint4*>(h);

    #pragma unroll
    for (int off = 32; off > 0; off >>= 1) ss += __shfl_down(ss, off, 64);
    if (lane == 0) norms[gwave] = ss;
}

// ------------- fused bf16 GEMM (F . P^T) + distance/sim/softmax --------------
// Block: 32 rows x ALL 2048 cols (softmax fully in-block). 8 waves.
// K streamed in 16 chunks of BK=32; each chunk processed as 2 column-halves of
// 1024 cols, double-buffered in LDS (64 KB each) via global_load_lds.
// LDS B row = 64 B (32 bf16 of k), XOR-swizzled: slot = j ^ ((col>>1)&3).
// Wave wid owns cols [wid*128, wid*128+128) within EACH half (acc idx h*8+ct).

__device__ __forceinline__ void stage_B(const ushort* __restrict__ Pb,
                                        ushort* lbuf, int h, int c,
                                        int wid, int ln) {
    #pragma unroll
    for (int r = 0; r < 8; ++r) {
        const int Lw  = r * 8192 + wid * 1024;       // wave-uniform LDS byte base
        const int myL = Lw + ln * 16;
        const int colh = myL >> 6;                   // col within half (64B rows)
        const int sl   = (myL >> 4) & 3;             // 16B slot within row
        const int j    = sl ^ ((colh >> 1) & 3);     // k-octet stored in this slot
        const ushort* src = Pb + ((size_t)(h * 1024 + colh) * D_DIM + c * 32 + 8 * j);
        gload16(src, (char*)lbuf + Lw);
    }
}

__device__ __forceinline__ void stage_A(const ushort* __restrict__ Fb,
                                        ushort* lbuf, int row0, int c,
                                        int wid, int ln) {
    if (wid < 2) {
        const int Lw  = wid * 1024;
        const int myL = Lw + ln * 16;
        const int rowa = myL >> 6;
        const int sl   = (myL >> 4) & 3;
        const int j    = sl ^ ((rowa >> 1) & 3);
        const ushort* src = Fb + ((size_t)(row0 + rowa) * D_DIM + c * 32 + 8 * j);
        gload16(src, (char*)lbuf + Lw);
    }
}

template <int H>
__device__ __forceinline__ void compute_half(const ushort* Abuf, const ushort* Bbuf,
                                             int wid, int lr, int lg,
                                             f4v acc[2][16]) {
    // A frags (rows rt*16+lr, k-octet lg), swizzled slot lookup
    const int r0 = lr, r1 = 16 + lr;
    s8v a0 = *(const s8v*)(Abuf + r0 * 32 + ((lg ^ ((r0 >> 1) & 3)) << 3));
    s8v a1 = *(const s8v*)(Abuf + r1 * 32 + ((lg ^ ((r1 >> 1) & 3)) << 3));
    #pragma unroll
    for (int ct = 0; ct < 8; ++ct) {
        const int cl = wid * 128 + ct * 16 + lr;     // col within half
        s8v b = *(const s8v*)(Bbuf + cl * 32 + ((lg ^ ((cl >> 1) & 3)) << 3));
        acc[0][H * 8 + ct] =
            __builtin_amdgcn_mfma_f32_16x16x32_bf16(a0, b, acc[0][H * 8 + ct], 0, 0, 0);
        acc[1][H * 8 + ct] =
            __builtin_amdgcn_mfma_f32_16x16x32_bf16(a1, b, acc[1][H * 8 + ct], 0, 0, 0);
    }
}

__global__ __launch_bounds__(512, 2)
void gemm_softmax_kernel(const ushort* __restrict__ Fb,
                         const ushort* __restrict__ Pb,
                         const float* __restrict__ f2,
                         const float* __restrict__ p2,
                         float* __restrict__ out) {
    __shared__ ushort Bb[2][1024 * 32];   // 2 x 64 KB: [buf==half][col][32k]
    __shared__ ushort Ab[2][32 * 32];     // 2 x 2 KB:  [chunk&1][row][32k]
    __shared__ float partial[8][BM];
    __shared__ float inv_total[BM];

    const int wid  = threadIdx.x >> 6;
    const int ln   = threadIdx.x & 63;
    const int lr   = ln & 15;
    const int lg   = ln >> 4;
    const int row0 = blockIdx.x * BM;

    f4v acc[2][16];
    #pragma unroll
    for (int rt = 0; rt < 2; ++rt)
        #pragma unroll
        for (int i = 0; i < 16; ++i)
            acc[rt][i] = (f4v){0.f, 0.f, 0.f, 0.f};

    // prologue: stage step 0 (half 0 of chunk 0) + A chunk 0
    stage_B(Pb, Bb[0], 0, 0, wid, ln);
    stage_A(Fb, Ab[0], row0, 0, wid, ln);
    __syncthreads();

    for (int c = 0; c < 16; ++c) {
        // ---- step h=0: compute half 0 of chunk c; stage half 1 of chunk c
        stage_B(Pb, Bb[1], 1, c, wid, ln);
        compute_half<0>(Ab[c & 1], Bb[0], wid, lr, lg, acc);
        __syncthreads();   // drains vmcnt -> Bb[1] ready

        // ---- step h=1: compute half 1; stage half 0 of chunk c+1 (+A)
        if (c < 15) {
            stage_B(Pb, Bb[0], 0, c + 1, wid, ln);
            stage_A(Fb, Ab[(c + 1) & 1], row0, c + 1, wid, ln);
        }
        compute_half<1>(Ab[c & 1], Bb[1], wid, lr, lg, acc);
        __syncthreads();
    }

    // ---- epilogue: sq = f2 + p2 - 2*fp ; sim = 1/(1+sqrt(sq)) ; e = exp(sim)
    float pf2[2][4];
    #pragma unroll
    for (int rt = 0; rt < 2; ++rt)
        #pragma unroll
        for (int r = 0; r < 4; ++r)
            pf2[rt][r] = f2[row0 + rt * 16 + 4 * lg + r];

    float pp2[16];
    #pragma unroll
    for (int i = 0; i < 16; ++i) {
        const int col = (i >> 3) * 1024 + wid * 128 + (i & 7) * 16 + lr;
        pp2[i] = p2[col];
    }

    float rsum[2][4] = {{0.f, 0.f, 0.f, 0.f}, {0.f, 0.f, 0.f, 0.f}};
    #pragma unroll
    for (int rt = 0; rt < 2; ++rt)
        #pragma unroll
        for (int i = 0; i < 16; ++i)
            #pragma unroll
            for (int r = 0; r < 4; ++r) {
                float sq = pf2[rt][r] + pp2[i] - 2.0f * acc[rt][i][r];
                sq = fmaxf(sq, 0.0f);
                float dist = sqrtf(sq);
                float e = __expf(1.0f / (1.0f + dist));
                acc[rt][i][r] = e;
                rsum[rt][r] += e;
            }

    #pragma unroll
    for (int rt = 0; rt < 2; ++rt)
        #pragma unroll
        for (int r = 0; r < 4; ++r) {
            float v = rsum[rt][r];
            #pragma unroll
            for (int m = 1; m < 16; m <<= 1) v += __shfl_xor(v, m, 64);
            rsum[rt][r] = v;
        }

    if (lr == 0) {
        #pragma unroll
        for (int rt = 0; rt < 2; ++rt)
            #pragma unroll
            for (int r = 0; r < 4; ++r)
                partial[wid][rt * 16 + 4 * lg + r] = rsum[rt][r];
    }
    __syncthreads();

    if (threadIdx.x < BM) {
        float s = 0.f;
        #pragma unroll
        for (int w = 0; w < 8; ++w) s += partial[w][threadIdx.x];
        inv_total[threadIdx.x] = 1.0f / s;
    }
    __syncthreads();

    float pinv[2][4];
    #pragma unroll
    for (int rt = 0; rt < 2; ++rt)
        #pragma unroll
        for (int r = 0; r < 4; ++r)
            pinv[rt][r] = inv_total[rt * 16 + 4 * lg + r];

    #pragma unroll
    for (int rt = 0; rt < 2; ++rt)
        #pragma unroll
        for (int i = 0; i < 16; ++i)
            #pragma unroll
            for (int r = 0; r < 4; ++r) {
                const int row = row0 + rt * 16 + 4 * lg + r;
                const int col = (i >> 3) * 1024 + wid * 128 + (i & 7) * 16 + lr;
                out[(size_t)row * K_CL + col] = acc[rt][i][r] * pinv[rt][r];
            }
}

extern "C" void kernel_launch(void* const* d_in, const int* in_sizes, int n_in,
                              void* d_out, int out_size, void* d_ws, size_t ws_size,
                              hipStream_t stream) {
    const float* features   = (const float*)d_in[0];
    const float* prototypes = (const float*)d_in[1];
    float* out = (float*)d_out;

    const int n = in_sizes[0] / D_DIM;   // 32768
    const int k = in_sizes[1] / D_DIM;   // 2048

    char* ws = (char*)d_ws;
    ushort* Fb = (ushort*)ws;                                    // n*D*2 bytes
    ushort* Pb = (ushort*)(ws + (size_t)n * D_DIM * 2);          // k*D*2 bytes
    float*  f2 = (float*)(ws + (size_t)(n + k) * D_DIM * 2);     // n floats
    float*  p2 = f2 + n;                                         // k floats

    prep_kernel<<<dim3((n + 3) / 4), dim3(256), 0, stream>>>(features, Fb, f2, n);
    prep_kernel<<<dim3((k + 3) / 4), dim3(256), 0, stream>>>(prototypes, Pb, p2, k);

    gemm_softmax_kernel<<<dim3(n / BM), dim3(512), 0, stream>>>(Fb, Pb, f2, p2, out);
}

// Round 3
// 252.657 us; speedup vs baseline: 1.4048x; 1.2517x over previous
//
#include <hip/hip_runtime.h>
#include <hip/hip_bf16.h>

#define D_DIM 512
#define K_CL  2048
#define BM    32

#define AS1 __attribute__((address_space(1)))
#define AS3 __attribute__((address_space(3)))

typedef short s8v __attribute__((ext_vector_type(8)));
typedef float f4v __attribute__((ext_vector_type(4)));

__device__ __forceinline__ void gload16(const void* g, void* l) {
    // async global->LDS, 16B/lane; LDS dest = wave-uniform base + lane*16
    __builtin_amdgcn_global_load_lds((const AS1 void*)g, (AS3 void*)l, 16, 0, 0);
}

// ---------------- prep F: fp32 -> bf16 row-major + row sum-of-squares --------
__global__ void prep_f_kernel(const float* __restrict__ src,
                              ushort* __restrict__ dst,
                              float* __restrict__ norms,
                              int nrows) {
    int gwave = (int)((blockIdx.x * blockDim.x + threadIdx.x) >> 6);
    int lane  = threadIdx.x & 63;
    if (gwave >= nrows) return;

    const float* row = src + (size_t)gwave * D_DIM + lane * 8;
    float4 v0 = *reinterpret_cast<const float4*>(row);
    float4 v1 = *reinterpret_cast<const float4*>(row + 4);

    float ss = v0.x * v0.x + v0.y * v0.y + v0.z * v0.z + v0.w * v0.w
             + v1.x * v1.x + v1.y * v1.y + v1.z * v1.z + v1.w * v1.w;

    alignas(16) __hip_bfloat16 h[8];
    h[0] = __float2bfloat16(v0.x); h[1] = __float2bfloat16(v0.y);
    h[2] = __float2bfloat16(v0.z); h[3] = __float2bfloat16(v0.w);
    h[4] = __float2bfloat16(v1.x); h[5] = __float2bfloat16(v1.y);
    h[6] = __float2bfloat16(v1.z); h[7] = __float2bfloat16(v1.w);
    *reinterpret_cast<uint4*>(dst + (size_t)gwave * D_DIM + lane * 8) =
        *reinterpret_cast<const uint4*>(h);

    #pragma unroll
    for (int off = 32; off > 0; off >>= 1) ss += __shfl_down(ss, off, 64);
    if (lane == 0) norms[gwave] = ss;
}

// -------- prep P: fp32 -> bf16 in STAGED layout (exact LDS image) + norms ----
// Staged layout: 64 quarter-chunk blocks of 32KB, block index (c*4 + qq),
// within block: colh*64B row, 16B slot sl = j ^ ((colh>>1)&3), j = k-octet.
__global__ void prep_p_kernel(const float* __restrict__ src,
                              ushort* __restrict__ dst,
                              float* __restrict__ norms) {
    int col  = (int)((blockIdx.x * blockDim.x + threadIdx.x) >> 6);
    int lane = threadIdx.x & 63;
    if (col >= K_CL) return;

    const float* row = src + (size_t)col * D_DIM + lane * 8;
    float4 v0 = *reinterpret_cast<const float4*>(row);
    float4 v1 = *reinterpret_cast<const float4*>(row + 4);

    float ss = v0.x * v0.x + v0.y * v0.y + v0.z * v0.z + v0.w * v0.w
             + v1.x * v1.x + v1.y * v1.y + v1.z * v1.z + v1.w * v1.w;

    alignas(16) __hip_bfloat16 h[8];
    h[0] = __float2bfloat16(v0.x); h[1] = __float2bfloat16(v0.y);
    h[2] = __float2bfloat16(v0.z); h[3] = __float2bfloat16(v0.w);
    h[4] = __float2bfloat16(v1.x); h[5] = __float2bfloat16(v1.y);
    h[6] = __float2bfloat16(v1.z); h[7] = __float2bfloat16(v1.w);

    const int c    = lane >> 2;          // k-chunk 0..15
    const int j    = lane & 3;           // k-octet within chunk
    const int qq   = col >> 9;           // quarter 0..3
    const int colh = col & 511;          // col within quarter
    const int sl   = j ^ ((colh >> 1) & 3);
    const size_t dsti = (size_t)(c * 4 + qq) * 16384 + colh * 32 + sl * 8;
    *reinterpret_cast<uint4*>(dst + dsti) = *reinterpret_cast<const uint4*>(h);

    #pragma unroll
    for (int off = 32; off > 0; off >>= 1) ss += __shfl_down(ss, off, 64);
    if (lane == 0) norms[col] = ss;
}

// ------------- fused bf16 GEMM (F . P^T) + distance/sim/softmax --------------
// Block: 32 rows x ALL 2048 cols. 8 waves. 64 phases; phase q computes quarter
// q (chunk cg=q>>2, cols (q&3)*512..+512) from ring slot q&3 (4 x 32KB ring,
// 2 quarters in flight, counted vmcnt(4), raw s_barrier — never drain to 0).

template <int QQ>
__device__ __forceinline__ void compute_phase(const ushort* bbuf, const ushort* abuf,
                                              int wid, int lr, int lg,
                                              f4v (&acc)[2][16]) {
    const int aswz = (lg ^ ((lr >> 1) & 3)) << 3;
    s8v a0 = *reinterpret_cast<const s8v*>(abuf + lr * 32 + aswz);
    s8v a1 = *reinterpret_cast<const s8v*>(abuf + (16 + lr) * 32 + aswz);
    #pragma unroll
    for (int ct = 0; ct < 4; ++ct) {
        const int cl = wid * 64 + ct * 16 + lr;   // col within quarter
        s8v b = *reinterpret_cast<const s8v*>(bbuf + cl * 32 + ((lg ^ ((cl >> 1) & 3)) << 3));
        acc[0][QQ * 4 + ct] =
            __builtin_amdgcn_mfma_f32_16x16x32_bf16(a0, b, acc[0][QQ * 4 + ct], 0, 0, 0);
        acc[1][QQ * 4 + ct] =
            __builtin_amdgcn_mfma_f32_16x16x32_bf16(a1, b, acc[1][QQ * 4 + ct], 0, 0, 0);
    }
}

__global__ __launch_bounds__(512, 2)
void gemm_softmax_kernel(const ushort* __restrict__ Fb,
                         const ushort* __restrict__ Ps,
                         const float* __restrict__ f2,
                         const float* __restrict__ p2,
                         float* __restrict__ out) {
    __shared__ ushort ring[4][16384];   // 4 x 32 KB quarter buffers
    __shared__ ushort Ab[2][1024];      // 2 x 2 KB A-chunk buffers
    __shared__ float partial[8][BM];
    __shared__ float inv_total[BM];

    const int tid = threadIdx.x;
    const int wid = tid >> 6;
    const int ln  = tid & 63;
    const int lr  = ln & 15;
    const int lg  = ln >> 4;
    const int row0 = blockIdx.x * BM;

    f4v acc[2][16];
    #pragma unroll
    for (int rt = 0; rt < 2; ++rt)
        #pragma unroll
        for (int i = 0; i < 16; ++i)
            acc[rt][i] = (f4v){0.f, 0.f, 0.f, 0.f};

    // linear stage of quarter q into ring slot (q&3): pure contiguous copy
    auto stageQ = [&](int q) {
        const ushort* src = Ps + (size_t)q * 16384;
        char* ldsbase = (char*)&ring[q & 3][0];
        #pragma unroll
        for (int r = 0; r < 4; ++r)
            gload16(src + r * 4096 + tid * 8, ldsbase + r * 8192 + wid * 1024);
    };
    // stage A chunk c (32 rows x 32 k) into Ab[c&1]; waves 0-1 only (1 gload)
    auto stageA = [&](int c) {
        if (wid < 2) {
            const int myL  = tid * 16;
            const int rowa = myL >> 6;
            const int sl   = (myL >> 4) & 3;
            const int j    = sl ^ ((rowa >> 1) & 3);
            const ushort* src = Fb + (size_t)(row0 + rowa) * D_DIM + c * 32 + 8 * j;
            gload16(src, (char*)&Ab[c & 1][0] + wid * 1024);
        }
    };

    // prologue: A chunk 0, quarters 0 and 1
    stageA(0);
    stageQ(0);
    stageQ(1);

#define PHASE(CG, QQ, VMFOUR, DO_Q, DO_A)                                     \
    {                                                                         \
        if (VMFOUR) asm volatile("s_waitcnt vmcnt(4)" ::: "memory");          \
        else        asm volatile("s_waitcnt vmcnt(0)" ::: "memory");          \
        __builtin_amdgcn_s_barrier();                                         \
        __builtin_amdgcn_sched_barrier(0);                                    \
        __builtin_amdgcn_s_setprio(1);                                        \
        compute_phase<QQ>(&ring[QQ][0], &Ab[(CG) & 1][0], wid, lr, lg, acc);  \
        __builtin_amdgcn_s_setprio(0);                                        \
        __builtin_amdgcn_sched_barrier(0);                                    \
        if (DO_A) stageA((CG) + 1);                                           \
        if (DO_Q) stageQ((CG) * 4 + QQ + 2);                                  \
    }

    for (int cg = 0; cg < 15; ++cg) {
        PHASE(cg, 0, true, true, false);
        PHASE(cg, 1, true, true, false);
        PHASE(cg, 2, true, true, false);
        PHASE(cg, 3, true, true, true);   // A for chunk cg+1 issued before Q
    }
    PHASE(15, 0, true, true,  false);     // stages quarter 62
    PHASE(15, 1, true, true,  false);     // stages quarter 63
    PHASE(15, 2, true, false, false);
    PHASE(15, 3, false, false, false);    // final: drain vmcnt(0)
#undef PHASE

    // ---- epilogue: sq = f2 + p2 - 2*fp ; sim = 1/(1+sqrt(sq)) ; softmax ----
    float pf2[2][4];
    #pragma unroll
    for (int rt = 0; rt < 2; ++rt)
        #pragma unroll
        for (int r = 0; r < 4; ++r)
            pf2[rt][r] = f2[row0 + rt * 16 + 4 * lg + r];

    float pp2[16];
    #pragma unroll
    for (int i = 0; i < 16; ++i) {
        const int col = (i >> 2) * 512 + wid * 64 + (i & 3) * 16 + lr;
        pp2[i] = p2[col];
    }

    float rsum[2][4] = {{0.f, 0.f, 0.f, 0.f}, {0.f, 0.f, 0.f, 0.f}};
    #pragma unroll
    for (int rt = 0; rt < 2; ++rt)
        #pragma unroll
        for (int i = 0; i < 16; ++i)
            #pragma unroll
            for (int r = 0; r < 4; ++r) {
                float sq = pf2[rt][r] + pp2[i] - 2.0f * acc[rt][i][r];
                sq = fmaxf(sq, 0.0f);
                float dist = sqrtf(sq);
                float e = __expf(1.0f / (1.0f + dist));
                acc[rt][i][r] = e;
                rsum[rt][r] += e;
            }

    #pragma unroll
    for (int rt = 0; rt < 2; ++rt)
        #pragma unroll
        for (int r = 0; r < 4; ++r) {
            float v = rsum[rt][r];
            #pragma unroll
            for (int m = 1; m < 16; m <<= 1) v += __shfl_xor(v, m, 64);
            rsum[rt][r] = v;
        }

    if (lr == 0) {
        #pragma unroll
        for (int rt = 0; rt < 2; ++rt)
            #pragma unroll
            for (int r = 0; r < 4; ++r)
                partial[wid][rt * 16 + 4 * lg + r] = rsum[rt][r];
    }
    __syncthreads();

    if (tid < BM) {
        float s = 0.f;
        #pragma unroll
        for (int w = 0; w < 8; ++w) s += partial[w][tid];
        inv_total[tid] = 1.0f / s;
    }
    __syncthreads();

    float pinv[2][4];
    #pragma unroll
    for (int rt = 0; rt < 2; ++rt)
        #pragma unroll
        for (int r = 0; r < 4; ++r)
            pinv[rt][r] = inv_total[rt * 16 + 4 * lg + r];

    #pragma unroll
    for (int rt = 0; rt < 2; ++rt)
        #pragma unroll
        for (int i = 0; i < 16; ++i)
            #pragma unroll
            for (int r = 0; r < 4; ++r) {
                const int row = row0 + rt * 16 + 4 * lg + r;
                const int col = (i >> 2) * 512 + wid * 64 + (i & 3) * 16 + lr;
                out[(size_t)row * K_CL + col] = acc[rt][i][r] * pinv[rt][r];
            }
}

extern "C" void kernel_launch(void* const* d_in, const int* in_sizes, int n_in,
                              void* d_out, int out_size, void* d_ws, size_t ws_size,
                              hipStream_t stream) {
    const float* features   = (const float*)d_in[0];
    const float* prototypes = (const float*)d_in[1];
    float* out = (float*)d_out;

    const int n = in_sizes[0] / D_DIM;   // 32768
    const int k = in_sizes[1] / D_DIM;   // 2048

    char* ws = (char*)d_ws;
    ushort* Fb = (ushort*)ws;                                    // n*D*2 bytes
    ushort* Ps = (ushort*)(ws + (size_t)n * D_DIM * 2);          // k*D*2 bytes (staged)
    float*  f2 = (float*)(ws + (size_t)(n + k) * D_DIM * 2);     // n floats
    float*  p2 = f2 + n;                                         // k floats

    prep_f_kernel<<<dim3((n + 3) / 4), dim3(256), 0, stream>>>(features, Fb, f2, n);
    prep_p_kernel<<<dim3((k + 3) / 4), dim3(256), 0, stream>>>(prototypes, Ps, p2);

    gemm_softmax_kernel<<<dim3(n / BM), dim3(512), 0, stream>>>(Fb, Ps, f2, p2, out);
}